// Round 13
// baseline (171.185 us; speedup 1.0000x reference)
//
#include <hip/hip_runtime.h>
#include <hip/hip_bf16.h>

typedef __attribute__((ext_vector_type(8))) short bf16x8;
typedef __attribute__((ext_vector_type(4))) float f32x4;
typedef __attribute__((ext_vector_type(4))) short s16x4;

#define M_DIM 4096   // B*S = 2*2048
#define N_DIM 4096   // D_out
#define K_DIM 4096   // D_in
#define R_DIM 4

__device__ __forceinline__ short to_bf16(float f) {
    __hip_bfloat16 h = __float2bfloat16(f);
    return *reinterpret_cast<short*>(&h);
}

// ---------------------------------------------------------------------------
// Kernel 1 (merged prep): blocks [0,8192): x_bf16 cast (pure BW);
// blocks [8192,12288): W_eff rows with tanh computed INLINE (the extra VALU
// hides under the concurrent x-cast blocks' HBM bottleneck).  Removes the
// separate k_prep launch + tB round-trip.  Same tanhf / same add order as
// the verified 3-launch version -> bit-identical weff.
// ---------------------------------------------------------------------------
__global__ __launch_bounds__(256)
void k_pre2(const float* __restrict__ x, __hip_bfloat16* __restrict__ xb,
            const float* __restrict__ w, const float* __restrict__ sA,
            const float* __restrict__ sB, const float* __restrict__ g,
            __hip_bfloat16* __restrict__ weff) {
    const int bid = blockIdx.x;
    if (bid < 8192) {
        const size_t i = ((size_t)bid * 256 + threadIdx.x) << 3;
        float4 u = *(const float4*)&x[i];
        float4 v = *(const float4*)&x[i + 4];
        bf16x8 pk;
        pk[0] = to_bf16(u.x); pk[1] = to_bf16(u.y);
        pk[2] = to_bf16(u.z); pk[3] = to_bf16(u.w);
        pk[4] = to_bf16(v.x); pk[5] = to_bf16(v.y);
        pk[6] = to_bf16(v.z); pk[7] = to_bf16(v.w);
        *(bf16x8*)&xb[i] = pk;
    } else {
        const int o = bid - 8192;
        const float a0 = tanhf(sA[o * 4 + 0]) * g[0];
        const float a1 = tanhf(sA[o * 4 + 1]) * g[1];
        const float a2 = tanhf(sA[o * 4 + 2]) * g[2];
        const float a3 = tanhf(sA[o * 4 + 3]) * g[3];
#pragma unroll
        for (int it = 0; it < 4; ++it) {
            const int i = (it * 256 + (int)threadIdx.x) << 2;
            float4 wv = *(const float4*)&w[(size_t)o * K_DIM + i];
            float4 r0 = *(const float4*)&sB[0 * K_DIM + i];
            float4 r1 = *(const float4*)&sB[1 * K_DIM + i];
            float4 r2 = *(const float4*)&sB[2 * K_DIM + i];
            float4 r3 = *(const float4*)&sB[3 * K_DIM + i];
            float4 b0, b1, b2, b3;
            b0.x = tanhf(r0.x); b0.y = tanhf(r0.y); b0.z = tanhf(r0.z); b0.w = tanhf(r0.w);
            b1.x = tanhf(r1.x); b1.y = tanhf(r1.y); b1.z = tanhf(r1.z); b1.w = tanhf(r1.w);
            b2.x = tanhf(r2.x); b2.y = tanhf(r2.y); b2.z = tanhf(r2.z); b2.w = tanhf(r2.w);
            b3.x = tanhf(r3.x); b3.y = tanhf(r3.y); b3.z = tanhf(r3.z); b3.w = tanhf(r3.w);
            float s0 = a0 * b0.x + a1 * b1.x + a2 * b2.x + a3 * b3.x;
            float s1 = a0 * b0.y + a1 * b1.y + a2 * b2.y + a3 * b3.y;
            float s2 = a0 * b0.z + a1 * b1.z + a2 * b2.z + a3 * b3.z;
            float s3 = a0 * b0.w + a1 * b1.w + a2 * b2.w + a3 * b3.w;
            s16x4 pk;
            pk[0] = to_bf16(wv.x * s0);
            pk[1] = to_bf16(wv.y * s1);
            pk[2] = to_bf16(wv.z * s2);
            pk[3] = to_bf16(wv.w * s3);
            *(s16x4*)&weff[(size_t)o * K_DIM + i] = pk;
        }
    }
}

// ---------------------------------------------------------------------------
// Kernel 2: out = x_bf16 @ weff^T + bias — round-12 verified kernel,
// UNCHANGED.  (4 merged phases / 2-K-tile iter, A tri-buffered, 160 KiB LDS,
// counted lgkmcnt split, bias folded into acc init.)
// ---------------------------------------------------------------------------
#define MFMA(A, B, C) __builtin_amdgcn_mfma_f32_16x16x32_bf16(A, B, C, 0, 0, 0)

#define RA0 0
#define RA1 32768
#define RA2 65536
#define SA0 0
#define SA1 16384
#define SA2 32768
#define SB0 49152
#define SB1 65536

#define RD_A_KS0(ab, qq) \
    aA = *(const bf16x8*)(LA0 + (ab) + (qq)*4096 + 0); \
    aC = *(const bf16x8*)(LA0 + (ab) + (qq)*4096 + 2048); \
    aE = *(const bf16x8*)(LA0 + (ab) + (qq)*4096 + 4096); \
    aG = *(const bf16x8*)(LA0 + (ab) + (qq)*4096 + 6144);

#define RD_A_KS1(ab, qq) \
    aB = *(const bf16x8*)(LA1 + (ab) + (qq)*4096 + 0); \
    aD = *(const bf16x8*)(LA1 + (ab) + (qq)*4096 + 2048); \
    aF = *(const bf16x8*)(LA1 + (ab) + (qq)*4096 + 4096); \
    aH = *(const bf16x8*)(LA1 + (ab) + (qq)*4096 + 6144);

#define RD_B_KS0(bb) \
    b0 = *(const bf16x8*)(LB0 + (bb) + 0); \
    b2 = *(const bf16x8*)(LB0 + (bb) + 2048); \
    b4 = *(const bf16x8*)(LB0 + (bb) + 4096); \
    b6 = *(const bf16x8*)(LB0 + (bb) + 6144);

#define RD_B_KS1(bb) \
    b1 = *(const bf16x8*)(LB1 + (bb) + 0); \
    b3 = *(const bf16x8*)(LB1 + (bb) + 2048); \
    b5 = *(const bf16x8*)(LB1 + (bb) + 4096); \
    b7 = *(const bf16x8*)(LB1 + (bb) + 6144);

#define MFMA16_KS0(qq) \
    acc[2*(qq)+0][0] = MFMA(aA, b0, acc[2*(qq)+0][0]); \
    acc[2*(qq)+0][1] = MFMA(aA, b2, acc[2*(qq)+0][1]); \
    acc[2*(qq)+0][2] = MFMA(aA, b4, acc[2*(qq)+0][2]); \
    acc[2*(qq)+0][3] = MFMA(aA, b6, acc[2*(qq)+0][3]); \
    acc[2*(qq)+1][0] = MFMA(aC, b0, acc[2*(qq)+1][0]); \
    acc[2*(qq)+1][1] = MFMA(aC, b2, acc[2*(qq)+1][1]); \
    acc[2*(qq)+1][2] = MFMA(aC, b4, acc[2*(qq)+1][2]); \
    acc[2*(qq)+1][3] = MFMA(aC, b6, acc[2*(qq)+1][3]); \
    acc[2*(qq)+2][0] = MFMA(aE, b0, acc[2*(qq)+2][0]); \
    acc[2*(qq)+2][1] = MFMA(aE, b2, acc[2*(qq)+2][1]); \
    acc[2*(qq)+2][2] = MFMA(aE, b4, acc[2*(qq)+2][2]); \
    acc[2*(qq)+2][3] = MFMA(aE, b6, acc[2*(qq)+2][3]); \
    acc[2*(qq)+3][0] = MFMA(aG, b0, acc[2*(qq)+3][0]); \
    acc[2*(qq)+3][1] = MFMA(aG, b2, acc[2*(qq)+3][1]); \
    acc[2*(qq)+3][2] = MFMA(aG, b4, acc[2*(qq)+3][2]); \
    acc[2*(qq)+3][3] = MFMA(aG, b6, acc[2*(qq)+3][3]);

#define MFMA16_KS1(qq) \
    acc[2*(qq)+0][0] = MFMA(aB, b1, acc[2*(qq)+0][0]); \
    acc[2*(qq)+0][1] = MFMA(aB, b3, acc[2*(qq)+0][1]); \
    acc[2*(qq)+0][2] = MFMA(aB, b5, acc[2*(qq)+0][2]); \
    acc[2*(qq)+0][3] = MFMA(aB, b7, acc[2*(qq)+0][3]); \
    acc[2*(qq)+1][0] = MFMA(aD, b1, acc[2*(qq)+1][0]); \
    acc[2*(qq)+1][1] = MFMA(aD, b3, acc[2*(qq)+1][1]); \
    acc[2*(qq)+1][2] = MFMA(aD, b5, acc[2*(qq)+1][2]); \
    acc[2*(qq)+1][3] = MFMA(aD, b7, acc[2*(qq)+1][3]); \
    acc[2*(qq)+2][0] = MFMA(aF, b1, acc[2*(qq)+2][0]); \
    acc[2*(qq)+2][1] = MFMA(aF, b3, acc[2*(qq)+2][1]); \
    acc[2*(qq)+2][2] = MFMA(aF, b5, acc[2*(qq)+2][2]); \
    acc[2*(qq)+2][3] = MFMA(aF, b7, acc[2*(qq)+2][3]); \
    acc[2*(qq)+3][0] = MFMA(aH, b1, acc[2*(qq)+3][0]); \
    acc[2*(qq)+3][1] = MFMA(aH, b3, acc[2*(qq)+3][1]); \
    acc[2*(qq)+3][2] = MFMA(aH, b5, acc[2*(qq)+3][2]); \
    acc[2*(qq)+3][3] = MFMA(aH, b7, acc[2*(qq)+3][3]);

#define VM4 asm volatile("s_waitcnt vmcnt(4)" ::: "memory")
#define SB0F __builtin_amdgcn_sched_barrier(0)

#define PH4(RD_KS0, RD_KS1, STAGE_STMT, VM_STMT, qq, LGK_ASM) \
    { RD_KS0; \
      SB0F; \
      RD_KS1; \
      STAGE_STMT; \
      VM_STMT; \
      __builtin_amdgcn_s_barrier(); \
      asm volatile(LGK_ASM ::: "memory"); \
      SB0F; \
      __builtin_amdgcn_s_setprio(1); \
      MFMA16_KS0(qq); \
      __builtin_amdgcn_s_setprio(0); \
      asm volatile("s_waitcnt lgkmcnt(0)" ::: "memory"); \
      SB0F; \
      __builtin_amdgcn_s_setprio(1); \
      MFMA16_KS1(qq); \
      __builtin_amdgcn_s_setprio(0); }

#define ITER4(RAu, RAv, SAu, SAw, KT1, KT2, KT3) \
    PH4(RD_A_KS0(RAu, 0); RD_B_KS0(0), RD_A_KS1(RAu, 0); RD_B_KS1(0), \
        STGT(gB, KT1, SB1), , 0, "s_waitcnt lgkmcnt(8)") \
    PH4(RD_A_KS0(RAu, 2), RD_A_KS1(RAu, 2), \
        STGT(gA, KT2, SAw), VM4, 2, "s_waitcnt lgkmcnt(4)") \
    PH4(RD_A_KS0(RAv, 0); RD_B_KS0(32768), RD_A_KS1(RAv, 0); RD_B_KS1(32768), \
        STGT(gB, KT2, SB0), , 0, "s_waitcnt lgkmcnt(8)") \
    PH4(RD_A_KS0(RAv, 2), RD_A_KS1(RAv, 2), \
        STGT(gA, KT3, SAu), VM4, 2, "s_waitcnt lgkmcnt(4)")

__global__ __launch_bounds__(512, 2)
void k_gemm8(const __hip_bfloat16* __restrict__ xb,
             const __hip_bfloat16* __restrict__ weff,
             const float* __restrict__ bias, float* __restrict__ out) {
    __shared__ short lds[81920];   // A0/A1/A2 @ 0/32768/65536 B; B0/B1 @ 98304/131072 B

    const int tid  = threadIdx.x;
    const int lane = tid & 63;
    const int wid  = tid >> 6;
    const int wr   = wid >> 2;
    const int wc   = wid & 3;
    const int l15  = lane & 15;
    const int cb0  = (lane >> 4) << 4;

    const int bid = blockIdx.x;
    const int swz = (bid & 7) * 32 + (bid >> 3);
    const int m0g = (swz >> 4) << 8;
    const int n0g = (swz & 15) << 8;

    const int mask = (l15 & 7) << 4;
    const int cbs0 = cb0 ^ mask;
    const int cbs1 = (cb0 + 64) ^ mask;
    const char* LAb = (const char*)lds + wr * 16384 + l15 * 128;
    const char* LA0 = LAb + cbs0;
    const char* LA1 = LAb + cbs1;
    const char* LBb = (const char*)lds + 98304 + (wc >> 1) * 16384 +
                      ((wc & 1) * 64 + l15) * 128;
    const char* LB0 = LBb + cbs0;
    const char* LB1 = LBb + cbs1;

    const int rowL  = tid >> 3;
    const int colbL = ((tid * 16) & 127) ^ ((rowL & 7) << 4);
    const __hip_bfloat16* gA = xb   + ((size_t)(m0g + rowL) << 12) + (colbL >> 1);
    const __hip_bfloat16* gB = weff + ((size_t)(n0g + rowL) << 12) + (colbL >> 1);

    auto STGT = [&](const __hip_bfloat16* gbase, int k0, int dstShort) {
#pragma unroll
        for (int p = 0; p < 4; ++p) {
            __builtin_amdgcn_global_load_lds(
                (const __attribute__((address_space(1))) void*)(gbase + p * 262144 + k0),
                (__attribute__((address_space(3))) void*)&lds[dstShort + p * 4096 + tid * 8],
                16, 0, 0);
        }
    };

    // bias folded into acc init
    f32x4 acc[8][4];
    {
        const float bv0 = bias[n0g + wc * 64 + 0  + l15];
        const float bv1 = bias[n0g + wc * 64 + 16 + l15];
        const float bv2 = bias[n0g + wc * 64 + 32 + l15];
        const float bv3 = bias[n0g + wc * 64 + 48 + l15];
#pragma unroll
        for (int m = 0; m < 8; ++m) {
#pragma unroll
            for (int j2 = 0; j2 < 4; ++j2) {
                acc[m][0][j2] = bv0;
                acc[m][1][j2] = bv1;
                acc[m][2][j2] = bv2;
                acc[m][3][j2] = bv3;
            }
        }
    }
    bf16x8 aA, aB, aC, aD, aE, aF, aG, aH;
    bf16x8 b0, b1, b2, b3, b4, b5, b6, b7;

    // prologue: B[0]<-t0, A[0]<-t0, A[1]<-t1, full drain
    STGT(gB, 0, SB0);
    STGT(gA, 0, SA0);
    STGT(gA, 64, SA1);
    asm volatile("s_waitcnt vmcnt(0)" ::: "memory");
    __builtin_amdgcn_s_barrier();
    SB0F;

    for (int j = 0; j < 10; ++j) {
        const int t = 6 * j;
        ITER4(RA0, RA1, SA0, SA2, (t + 1) * 64, (t + 2) * 64, (t + 3) * 64);
        ITER4(RA2, RA0, SA2, SA1, (t + 3) * 64, (t + 4) * 64, (t + 5) * 64);
        ITER4(RA1, RA2, SA1, SA0, (t + 5) * 64, (t + 6) * 64, (t + 7) * 64);
    }
    ITER4(RA0, RA1, SA0, SA2, 61 * 64, 62 * 64, 63 * 64);
    ITER4(RA2, RA0, SA2, SA1, 63 * 64, 63 * 64, 63 * 64);

    // epilogue: C/D map col=lane&15, row=(lane>>4)*4+j (bias already in acc)
#pragma unroll
    for (int n = 0; n < 4; ++n) {
        const int col = n0g + wc * 64 + n * 16 + l15;
#pragma unroll
        for (int m = 0; m < 8; ++m) {
            const int rbase = m0g + wr * 128 + m * 16 + ((lane >> 4) << 2);
#pragma unroll
            for (int j2 = 0; j2 < 4; ++j2)
                out[(size_t)(rbase + j2) * N_DIM + col] = acc[m][n][j2];
        }
    }
}

// ---------------------------------------------------------------------------
extern "C" void kernel_launch(void* const* d_in, const int* in_sizes, int n_in,
                              void* d_out, int out_size, void* d_ws, size_t ws_size,
                              hipStream_t stream) {
    const float* x    = (const float*)d_in[0];  // [2,2048,4096]
    const float* w    = (const float*)d_in[1];  // [4096,4096]
    const float* bias = (const float*)d_in[2];  // [4096]
    const float* sA   = (const float*)d_in[3];  // [4096,4]
    const float* sB   = (const float*)d_in[4];  // [4,4096]
    const float* g    = (const float*)d_in[5];  // [4]
    float* out = (float*)d_out;

    // [weff bf16: 32MB][x_bf16: 32MB]
    __hip_bfloat16* weff = (__hip_bfloat16*)d_ws;
    __hip_bfloat16* xb   = (__hip_bfloat16*)((char*)d_ws + (32ull << 20));

    k_pre2<<<dim3(8192 + N_DIM), dim3(256), 0, stream>>>(x, xb, w, sA, sB, g, weff);
    k_gemm8<<<dim3((M_DIM / 256) * (N_DIM / 256)), dim3(512), 0, stream>>>(xb, weff, bias, out);
}

// Round 14
// 149.816 us; speedup vs baseline: 1.1426x; 1.1426x over previous
//
#include <hip/hip_runtime.h>
#include <hip/hip_bf16.h>

typedef __attribute__((ext_vector_type(8))) short bf16x8;
typedef __attribute__((ext_vector_type(4))) float f32x4;
typedef __attribute__((ext_vector_type(4))) short s16x4;

#define M_DIM 4096   // B*S = 2*2048
#define N_DIM 4096   // D_out
#define K_DIM 4096   // D_in
#define R_DIM 4

__device__ __forceinline__ short to_bf16(float f) {
    __hip_bfloat16 h = __float2bfloat16(f);
    return *reinterpret_cast<short*>(&h);
}

// ---------------------------------------------------------------------------
// Kernel 1: tB[r][i] = tanh(scale_B[r,i]); tAg[o][r] = tanh(scale_A[o,r])*g[r]
// (tanh computed ONCE here — round 13 proved inlining it into k_pre2 costs
// 268M redundant tanhf and +21 µs.)
// ---------------------------------------------------------------------------
__global__ __launch_bounds__(256)
void k_prep(const float* __restrict__ sA, const float* __restrict__ sB,
            const float* __restrict__ g, float* __restrict__ tB,
            float* __restrict__ tAg) {
    int i = blockIdx.x * 256 + threadIdx.x;
    if (i < R_DIM * K_DIM) {
        tB[i] = tanhf(sB[i]);
    } else {
        int j = i - R_DIM * K_DIM;   // j = o*4 + r
        tAg[j] = tanhf(sA[j]) * g[j & 3];
    }
}

// ---------------------------------------------------------------------------
// Kernel 2 (merged): blocks [0,8192): x_bf16 cast; blocks [8192,12288):
// W_eff row computation from precomputed tB/tAg.  Both pure-BW.
// ---------------------------------------------------------------------------
__global__ __launch_bounds__(256)
void k_pre2(const float* __restrict__ x, __hip_bfloat16* __restrict__ xb,
            const float* __restrict__ w, const float* __restrict__ tB,
            const float* __restrict__ tAg, __hip_bfloat16* __restrict__ weff) {
    const int bid = blockIdx.x;
    if (bid < 8192) {
        const size_t i = ((size_t)bid * 256 + threadIdx.x) << 3;
        float4 u = *(const float4*)&x[i];
        float4 v = *(const float4*)&x[i + 4];
        bf16x8 pk;
        pk[0] = to_bf16(u.x); pk[1] = to_bf16(u.y);
        pk[2] = to_bf16(u.z); pk[3] = to_bf16(u.w);
        pk[4] = to_bf16(v.x); pk[5] = to_bf16(v.y);
        pk[6] = to_bf16(v.z); pk[7] = to_bf16(v.w);
        *(bf16x8*)&xb[i] = pk;
    } else {
        const int o = bid - 8192;
        const float a0 = tAg[o * 4 + 0];
        const float a1 = tAg[o * 4 + 1];
        const float a2 = tAg[o * 4 + 2];
        const float a3 = tAg[o * 4 + 3];
#pragma unroll
        for (int it = 0; it < 4; ++it) {
            const int i = (it * 256 + (int)threadIdx.x) << 2;
            float4 wv = *(const float4*)&w[(size_t)o * K_DIM + i];
            float4 b0 = *(const float4*)&tB[0 * K_DIM + i];
            float4 b1 = *(const float4*)&tB[1 * K_DIM + i];
            float4 b2 = *(const float4*)&tB[2 * K_DIM + i];
            float4 b3 = *(const float4*)&tB[3 * K_DIM + i];
            float s0 = a0 * b0.x + a1 * b1.x + a2 * b2.x + a3 * b3.x;
            float s1 = a0 * b0.y + a1 * b1.y + a2 * b2.y + a3 * b3.y;
            float s2 = a0 * b0.z + a1 * b1.z + a2 * b2.z + a3 * b3.z;
            float s3 = a0 * b0.w + a1 * b1.w + a2 * b2.w + a3 * b3.w;
            s16x4 pk;
            pk[0] = to_bf16(wv.x * s0);
            pk[1] = to_bf16(wv.y * s1);
            pk[2] = to_bf16(wv.z * s2);
            pk[3] = to_bf16(wv.w * s3);
            *(s16x4*)&weff[(size_t)o * K_DIM + i] = pk;
        }
    }
}

// ---------------------------------------------------------------------------
// Kernel 3: out = x_bf16 @ weff^T + bias — round-12 verified kernel,
// UNCHANGED.  (256x256 tile, 4 merged phases / 2-K-tile iter, A tri-buffered,
// 160 KiB LDS, counted lgkmcnt split, bias folded into acc init.)
// ---------------------------------------------------------------------------
#define MFMA(A, B, C) __builtin_amdgcn_mfma_f32_16x16x32_bf16(A, B, C, 0, 0, 0)

#define RA0 0
#define RA1 32768
#define RA2 65536
#define SA0 0
#define SA1 16384
#define SA2 32768
#define SB0 49152
#define SB1 65536

#define RD_A_KS0(ab, qq) \
    aA = *(const bf16x8*)(LA0 + (ab) + (qq)*4096 + 0); \
    aC = *(const bf16x8*)(LA0 + (ab) + (qq)*4096 + 2048); \
    aE = *(const bf16x8*)(LA0 + (ab) + (qq)*4096 + 4096); \
    aG = *(const bf16x8*)(LA0 + (ab) + (qq)*4096 + 6144);

#define RD_A_KS1(ab, qq) \
    aB = *(const bf16x8*)(LA1 + (ab) + (qq)*4096 + 0); \
    aD = *(const bf16x8*)(LA1 + (ab) + (qq)*4096 + 2048); \
    aF = *(const bf16x8*)(LA1 + (ab) + (qq)*4096 + 4096); \
    aH = *(const bf16x8*)(LA1 + (ab) + (qq)*4096 + 6144);

#define RD_B_KS0(bb) \
    b0 = *(const bf16x8*)(LB0 + (bb) + 0); \
    b2 = *(const bf16x8*)(LB0 + (bb) + 2048); \
    b4 = *(const bf16x8*)(LB0 + (bb) + 4096); \
    b6 = *(const bf16x8*)(LB0 + (bb) + 6144);

#define RD_B_KS1(bb) \
    b1 = *(const bf16x8*)(LB1 + (bb) + 0); \
    b3 = *(const bf16x8*)(LB1 + (bb) + 2048); \
    b5 = *(const bf16x8*)(LB1 + (bb) + 4096); \
    b7 = *(const bf16x8*)(LB1 + (bb) + 6144);

#define MFMA16_KS0(qq) \
    acc[2*(qq)+0][0] = MFMA(aA, b0, acc[2*(qq)+0][0]); \
    acc[2*(qq)+0][1] = MFMA(aA, b2, acc[2*(qq)+0][1]); \
    acc[2*(qq)+0][2] = MFMA(aA, b4, acc[2*(qq)+0][2]); \
    acc[2*(qq)+0][3] = MFMA(aA, b6, acc[2*(qq)+0][3]); \
    acc[2*(qq)+1][0] = MFMA(aC, b0, acc[2*(qq)+1][0]); \
    acc[2*(qq)+1][1] = MFMA(aC, b2, acc[2*(qq)+1][1]); \
    acc[2*(qq)+1][2] = MFMA(aC, b4, acc[2*(qq)+1][2]); \
    acc[2*(qq)+1][3] = MFMA(aC, b6, acc[2*(qq)+1][3]); \
    acc[2*(qq)+2][0] = MFMA(aE, b0, acc[2*(qq)+2][0]); \
    acc[2*(qq)+2][1] = MFMA(aE, b2, acc[2*(qq)+2][1]); \
    acc[2*(qq)+2][2] = MFMA(aE, b4, acc[2*(qq)+2][2]); \
    acc[2*(qq)+2][3] = MFMA(aE, b6, acc[2*(qq)+2][3]); \
    acc[2*(qq)+3][0] = MFMA(aG, b0, acc[2*(qq)+3][0]); \
    acc[2*(qq)+3][1] = MFMA(aG, b2, acc[2*(qq)+3][1]); \
    acc[2*(qq)+3][2] = MFMA(aG, b4, acc[2*(qq)+3][2]); \
    acc[2*(qq)+3][3] = MFMA(aG, b6, acc[2*(qq)+3][3]);

#define MFMA16_KS1(qq) \
    acc[2*(qq)+0][0] = MFMA(aB, b1, acc[2*(qq)+0][0]); \
    acc[2*(qq)+0][1] = MFMA(aB, b3, acc[2*(qq)+0][1]); \
    acc[2*(qq)+0][2] = MFMA(aB, b5, acc[2*(qq)+0][2]); \
    acc[2*(qq)+0][3] = MFMA(aB, b7, acc[2*(qq)+0][3]); \
    acc[2*(qq)+1][0] = MFMA(aD, b1, acc[2*(qq)+1][0]); \
    acc[2*(qq)+1][1] = MFMA(aD, b3, acc[2*(qq)+1][1]); \
    acc[2*(qq)+1][2] = MFMA(aD, b5, acc[2*(qq)+1][2]); \
    acc[2*(qq)+1][3] = MFMA(aD, b7, acc[2*(qq)+1][3]); \
    acc[2*(qq)+2][0] = MFMA(aF, b1, acc[2*(qq)+2][0]); \
    acc[2*(qq)+2][1] = MFMA(aF, b3, acc[2*(qq)+2][1]); \
    acc[2*(qq)+2][2] = MFMA(aF, b5, acc[2*(qq)+2][2]); \
    acc[2*(qq)+2][3] = MFMA(aF, b7, acc[2*(qq)+2][3]); \
    acc[2*(qq)+3][0] = MFMA(aH, b1, acc[2*(qq)+3][0]); \
    acc[2*(qq)+3][1] = MFMA(aH, b3, acc[2*(qq)+3][1]); \
    acc[2*(qq)+3][2] = MFMA(aH, b5, acc[2*(qq)+3][2]); \
    acc[2*(qq)+3][3] = MFMA(aH, b7, acc[2*(qq)+3][3]);

#define VM4 asm volatile("s_waitcnt vmcnt(4)" ::: "memory")
#define SB0F __builtin_amdgcn_sched_barrier(0)

#define PH4(RD_KS0, RD_KS1, STAGE_STMT, VM_STMT, qq, LGK_ASM) \
    { RD_KS0; \
      SB0F; \
      RD_KS1; \
      STAGE_STMT; \
      VM_STMT; \
      __builtin_amdgcn_s_barrier(); \
      asm volatile(LGK_ASM ::: "memory"); \
      SB0F; \
      __builtin_amdgcn_s_setprio(1); \
      MFMA16_KS0(qq); \
      __builtin_amdgcn_s_setprio(0); \
      asm volatile("s_waitcnt lgkmcnt(0)" ::: "memory"); \
      SB0F; \
      __builtin_amdgcn_s_setprio(1); \
      MFMA16_KS1(qq); \
      __builtin_amdgcn_s_setprio(0); }

#define ITER4(RAu, RAv, SAu, SAw, KT1, KT2, KT3) \
    PH4(RD_A_KS0(RAu, 0); RD_B_KS0(0), RD_A_KS1(RAu, 0); RD_B_KS1(0), \
        STGT(gB, KT1, SB1), , 0, "s_waitcnt lgkmcnt(8)") \
    PH4(RD_A_KS0(RAu, 2), RD_A_KS1(RAu, 2), \
        STGT(gA, KT2, SAw), VM4, 2, "s_waitcnt lgkmcnt(4)") \
    PH4(RD_A_KS0(RAv, 0); RD_B_KS0(32768), RD_A_KS1(RAv, 0); RD_B_KS1(32768), \
        STGT(gB, KT2, SB0), , 0, "s_waitcnt lgkmcnt(8)") \
    PH4(RD_A_KS0(RAv, 2), RD_A_KS1(RAv, 2), \
        STGT(gA, KT3, SAu), VM4, 2, "s_waitcnt lgkmcnt(4)")

__global__ __launch_bounds__(512, 2)
void k_gemm8(const __hip_bfloat16* __restrict__ xb,
             const __hip_bfloat16* __restrict__ weff,
             const float* __restrict__ bias, float* __restrict__ out) {
    __shared__ short lds[81920];   // A0/A1/A2 @ 0/32768/65536 B; B0/B1 @ 98304/131072 B

    const int tid  = threadIdx.x;
    const int lane = tid & 63;
    const int wid  = tid >> 6;
    const int wr   = wid >> 2;
    const int wc   = wid & 3;
    const int l15  = lane & 15;
    const int cb0  = (lane >> 4) << 4;

    const int bid = blockIdx.x;
    const int swz = (bid & 7) * 32 + (bid >> 3);
    const int m0g = (swz >> 4) << 8;
    const int n0g = (swz & 15) << 8;

    const int mask = (l15 & 7) << 4;
    const int cbs0 = cb0 ^ mask;
    const int cbs1 = (cb0 + 64) ^ mask;
    const char* LAb = (const char*)lds + wr * 16384 + l15 * 128;
    const char* LA0 = LAb + cbs0;
    const char* LA1 = LAb + cbs1;
    const char* LBb = (const char*)lds + 98304 + (wc >> 1) * 16384 +
                      ((wc & 1) * 64 + l15) * 128;
    const char* LB0 = LBb + cbs0;
    const char* LB1 = LBb + cbs1;

    const int rowL  = tid >> 3;
    const int colbL = ((tid * 16) & 127) ^ ((rowL & 7) << 4);
    const __hip_bfloat16* gA = xb   + ((size_t)(m0g + rowL) << 12) + (colbL >> 1);
    const __hip_bfloat16* gB = weff + ((size_t)(n0g + rowL) << 12) + (colbL >> 1);

    auto STGT = [&](const __hip_bfloat16* gbase, int k0, int dstShort) {
#pragma unroll
        for (int p = 0; p < 4; ++p) {
            __builtin_amdgcn_global_load_lds(
                (const __attribute__((address_space(1))) void*)(gbase + p * 262144 + k0),
                (__attribute__((address_space(3))) void*)&lds[dstShort + p * 4096 + tid * 8],
                16, 0, 0);
        }
    };

    // bias folded into acc init
    f32x4 acc[8][4];
    {
        const float bv0 = bias[n0g + wc * 64 + 0  + l15];
        const float bv1 = bias[n0g + wc * 64 + 16 + l15];
        const float bv2 = bias[n0g + wc * 64 + 32 + l15];
        const float bv3 = bias[n0g + wc * 64 + 48 + l15];
#pragma unroll
        for (int m = 0; m < 8; ++m) {
#pragma unroll
            for (int j2 = 0; j2 < 4; ++j2) {
                acc[m][0][j2] = bv0;
                acc[m][1][j2] = bv1;
                acc[m][2][j2] = bv2;
                acc[m][3][j2] = bv3;
            }
        }
    }
    bf16x8 aA, aB, aC, aD, aE, aF, aG, aH;
    bf16x8 b0, b1, b2, b3, b4, b5, b6, b7;

    // prologue: B[0]<-t0, A[0]<-t0, A[1]<-t1, full drain
    STGT(gB, 0, SB0);
    STGT(gA, 0, SA0);
    STGT(gA, 64, SA1);
    asm volatile("s_waitcnt vmcnt(0)" ::: "memory");
    __builtin_amdgcn_s_barrier();
    SB0F;

    for (int j = 0; j < 10; ++j) {
        const int t = 6 * j;
        ITER4(RA0, RA1, SA0, SA2, (t + 1) * 64, (t + 2) * 64, (t + 3) * 64);
        ITER4(RA2, RA0, SA2, SA1, (t + 3) * 64, (t + 4) * 64, (t + 5) * 64);
        ITER4(RA1, RA2, SA1, SA0, (t + 5) * 64, (t + 6) * 64, (t + 7) * 64);
    }
    ITER4(RA0, RA1, SA0, SA2, 61 * 64, 62 * 64, 63 * 64);
    ITER4(RA2, RA0, SA2, SA1, 63 * 64, 63 * 64, 63 * 64);

    // epilogue: C/D map col=lane&15, row=(lane>>4)*4+j (bias already in acc)
#pragma unroll
    for (int n = 0; n < 4; ++n) {
        const int col = n0g + wc * 64 + n * 16 + l15;
#pragma unroll
        for (int m = 0; m < 8; ++m) {
            const int rbase = m0g + wr * 128 + m * 16 + ((lane >> 4) << 2);
#pragma unroll
            for (int j2 = 0; j2 < 4; ++j2)
                out[(size_t)(rbase + j2) * N_DIM + col] = acc[m][n][j2];
        }
    }
}

// ---------------------------------------------------------------------------
extern "C" void kernel_launch(void* const* d_in, const int* in_sizes, int n_in,
                              void* d_out, int out_size, void* d_ws, size_t ws_size,
                              hipStream_t stream) {
    const float* x    = (const float*)d_in[0];  // [2,2048,4096]
    const float* w    = (const float*)d_in[1];  // [4096,4096]
    const float* bias = (const float*)d_in[2];  // [4096]
    const float* sA   = (const float*)d_in[3];  // [4096,4]
    const float* sB   = (const float*)d_in[4];  // [4,4096]
    const float* g    = (const float*)d_in[5];  // [4]
    float* out = (float*)d_out;

    // [weff bf16: 32MB][x_bf16: 32MB][tB f32: 64KB][tAg f32: 64KB]
    __hip_bfloat16* weff = (__hip_bfloat16*)d_ws;
    __hip_bfloat16* xb   = (__hip_bfloat16*)((char*)d_ws + (32ull << 20));
    float* tB  = (float*)((char*)d_ws + (64ull << 20));
    float* tAg = (float*)((char*)d_ws + (64ull << 20) + (R_DIM * K_DIM * 4));

    k_prep<<<dim3((2 * R_DIM * K_DIM) / 256), dim3(256), 0, stream>>>(sA, sB, g, tB, tAg);
    k_pre2<<<dim3(8192 + N_DIM), dim3(256), 0, stream>>>(x, xb, w, tB, tAg, weff);
    k_gemm8<<<dim3((M_DIM / 256) * (N_DIM / 256)), dim3(512), 0, stream>>>(xb, weff, bias, out);
}